// Round 7
// baseline (166.939 us; speedup 1.0000x reference)
//
#include <hip/hip_runtime.h>

#define NPTS  8192
#define DIM   512
#define NK    64
#define BM    32            // rows per tile
#define KH    256           // dims per K-half (per gemm block)
#define CHK   128           // dims per staged chunk (2 chunks per block)
#define NTILE (NPTS/BM)     // 256 tiles; grid = 512 (x2 K-halves)

// workspace layout (float offsets)
#define WS_DOT  0                              // [256][2][32][64] = 1048576 f
#define WS_STAT (NTILE*2*BM*NK)                // [256][2][32] float2 = 32768 f
#define WS_CTT  (WS_STAT + NTILE*2*BM*2)       // [512][64] = 32768 f
#define WS_SQC  (WS_CTT + DIM*NK)              // [64]
#define WS_SC   (WS_SQC + NK)                  // [64]

// ---------------------------------------------------------------------------
// Prep: gather centroid rows into transposed ctT[d][n] (so gemm's B staging is
// a linear copy), per-centroid stats, zero the energy accumulator.
// ---------------------------------------------------------------------------
__global__ __launch_bounds__(64) void prep_kernel(
    const float* __restrict__ f, const int* __restrict__ cid,
    float* __restrict__ ws, float* __restrict__ out)
{
    const int k = blockIdx.x;      // one wave per centroid
    const int lane = threadIdx.x;
    if (k == 0 && lane == 0) out[0] = 0.f;   // stream order: before epi atomics
    float* ctT = ws + WS_CTT;
    const float* row = f + (size_t)cid[k] * DIM;
    float4 a = *(const float4*)(row + lane * 8);
    float4 b = *(const float4*)(row + lane * 8 + 4);
    const int d = lane * 8;
    ctT[(d+0)*NK + k] = a.x;  ctT[(d+1)*NK + k] = a.y;
    ctT[(d+2)*NK + k] = a.z;  ctT[(d+3)*NK + k] = a.w;
    ctT[(d+4)*NK + k] = b.x;  ctT[(d+5)*NK + k] = b.y;
    ctT[(d+6)*NK + k] = b.z;  ctT[(d+7)*NK + k] = b.w;
    float s = a.x+a.y+a.z+a.w + b.x+b.y+b.z+b.w;
    float q = a.x*a.x+a.y*a.y+a.z*a.z+a.w*a.w
            + b.x*b.x+b.y*b.y+b.z*b.z+b.w*b.w;
    #pragma unroll
    for (int off = 32; off; off >>= 1) {
        s += __shfl_xor(s, off);
        q += __shfl_xor(q, off);
    }
    if (lane == 0) { ws[WS_SQC + k] = q; ws[WS_SC + k] = s; }
}

// ---------------------------------------------------------------------------
// GEMM: 512 blocks (256 tiles x 2 K-halves) x 512 threads -> 2 blocks/CU so
// barriers/stalls of one block overlap the other block's compute (R2/R5 were
// 1 block/CU and latency-bound at ~29us despite a 2x LDS-traffic difference).
// Per block: 32x64 tile over 256 dims, 2 chunks of 128; BOTH chunks' global
// fragments loaded to regs in the prologue (HBM latency hidden under chunk-0
// compute). 8 waves = 16-dim K-slices; thread microtile 4x8 (acc static).
// ---------------------------------------------------------------------------
__global__ __launch_bounds__(512, 4) void gemm_kernel(
    const float* __restrict__ f, float* __restrict__ ws)
{
    __shared__ float Al[CHK * BM];        // [k][row] 16 KB, k-major
    __shared__ float Bl[CHK * NK];        // [k][col] 32 KB
    __shared__ float statS[8][BM], statQ[8][BM];   // 1 KB

    const int t    = threadIdx.x;
    const int lane = t & 63;
    const int w    = t >> 6;          // wave id = K-slice within chunk
    const int rg   = lane & 7;
    const int cg   = lane >> 3;
    const int tile  = blockIdx.x & (NTILE - 1);
    const int khalf = blockIdx.x >> 8;
    const int kbase = khalf * KH;

    // staging roles: A row = t&31, f4-slot = t>>5 (and +16); B linear.
    const int arow = t & 31;
    const int ak4  = t >> 5;
    const float* fA = f + (size_t)(tile * BM + arow) * DIM + kbase;
    const float* Bg = ws + WS_CTT + (size_t)kbase * NK;

    // ---- prologue: load BOTH chunks' fragments into registers ----
    float4 a0c0 = *(const float4*)(fA + ak4 * 4);
    float4 a1c0 = *(const float4*)(fA + (ak4 + 16) * 4);
    float4 a0c1 = *(const float4*)(fA + CHK + ak4 * 4);
    float4 a1c1 = *(const float4*)(fA + CHK + (ak4 + 16) * 4);
    float4 bc0[4], bc1[4];
    #pragma unroll
    for (int j = 0; j < 4; ++j) {
        bc0[j] = *(const float4*)(Bg + (size_t)(t + 512 * j) * 4);
        bc1[j] = *(const float4*)(Bg + (size_t)CHK * NK + (t + 512 * j) * 4);
    }

    // row stats over this thread's fragments (full K-half slice of row arow)
    float sp = 0.f, qp = 0.f;
#define STAT4(v) do { sp += v.x+v.y+v.z+v.w; \
                      qp += v.x*v.x+v.y*v.y+v.z*v.z+v.w*v.w; } while (0)
    STAT4(a0c0); STAT4(a1c0); STAT4(a0c1); STAT4(a1c1);
#undef STAT4
    sp += __shfl_xor(sp, 32);          // lanes l, l+32 share arow
    qp += __shfl_xor(qp, 32);

#define AWRITE(k4, v) do { int kk_ = (k4) * 4; \
        Al[(kk_+0)*BM + arow] = v.x; Al[(kk_+1)*BM + arow] = v.y; \
        Al[(kk_+2)*BM + arow] = v.z; Al[(kk_+3)*BM + arow] = v.w; } while (0)

    // ---- stage chunk 0 ----
    AWRITE(ak4, a0c0); AWRITE(ak4 + 16, a1c0);
    #pragma unroll
    for (int j = 0; j < 4; ++j) *(float4*)&Bl[(t + 512 * j) * 4] = bc0[j];
    __syncthreads();

    float acc[4][8];
    #pragma unroll
    for (int r = 0; r < 4; ++r)
        #pragma unroll
        for (int c = 0; c < 8; ++c) acc[r][c] = 0.f;

#define COMPUTE_CHUNK()                                                        \
    _Pragma("unroll")                                                          \
    for (int kq = 0; kq < 16; ++kq) {                                          \
        const int k = w * 16 + kq;                                             \
        float4 av = *(const float4*)&Al[k * BM + rg * 4];                      \
        float4 b0 = *(const float4*)&Bl[k * NK + cg * 8];                      \
        float4 b1 = *(const float4*)&Bl[k * NK + cg * 8 + 4];                  \
        const float a4[4] = {av.x, av.y, av.z, av.w};                          \
        _Pragma("unroll")                                                      \
        for (int r = 0; r < 4; ++r) {                                          \
            acc[r][0] = fmaf(a4[r], b0.x, acc[r][0]);                          \
            acc[r][1] = fmaf(a4[r], b0.y, acc[r][1]);                          \
            acc[r][2] = fmaf(a4[r], b0.z, acc[r][2]);                          \
            acc[r][3] = fmaf(a4[r], b0.w, acc[r][3]);                          \
            acc[r][4] = fmaf(a4[r], b1.x, acc[r][4]);                          \
            acc[r][5] = fmaf(a4[r], b1.y, acc[r][5]);                          \
            acc[r][6] = fmaf(a4[r], b1.z, acc[r][6]);                          \
            acc[r][7] = fmaf(a4[r], b1.w, acc[r][7]);                          \
        }                                                                      \
    }

    COMPUTE_CHUNK();          // chunk 0
    __syncthreads();          // chunk-0 LDS reads done
    AWRITE(ak4, a0c1); AWRITE(ak4 + 16, a1c1);
    #pragma unroll
    for (int j = 0; j < 4; ++j) *(float4*)&Bl[(t + 512 * j) * 4] = bc1[j];
    __syncthreads();
    COMPUTE_CHUNK();          // chunk 1
#undef COMPUTE_CHUNK
#undef AWRITE

    if (lane < BM) { statS[w][lane] = sp; statQ[w][lane] = qp; }
    __syncthreads();          // compute-1 LDS reads done; A/B LDS now dead

    // ---- tree-combine 8 wave partials through dead A/B LDS ----
#define ACC_STORE(base) do { float* d_ = (base) + (size_t)(rg*4)*NK + cg*8;    \
        _Pragma("unroll") for (int r = 0; r < 4; ++r) {                        \
            *(float4*)(d_ + r*NK)     = make_float4(acc[r][0],acc[r][1],acc[r][2],acc[r][3]); \
            *(float4*)(d_ + r*NK + 4) = make_float4(acc[r][4],acc[r][5],acc[r][6],acc[r][7]); } } while (0)
#define ACC_LOAD_ADD(base) do { const float* s_ = (base) + (size_t)(rg*4)*NK + cg*8; \
        _Pragma("unroll") for (int r = 0; r < 4; ++r) {                        \
            float4 v0 = *(const float4*)(s_ + r*NK);                           \
            float4 v1 = *(const float4*)(s_ + r*NK + 4);                       \
            acc[r][0]+=v0.x; acc[r][1]+=v0.y; acc[r][2]+=v0.z; acc[r][3]+=v0.w;\
            acc[r][4]+=v1.x; acc[r][5]+=v1.y; acc[r][6]+=v1.z; acc[r][7]+=v1.w; } } while (0)

    if (w >= 4) ACC_STORE(Bl + (w - 4) * (BM * NK));
    __syncthreads();
    if (w < 4)  ACC_LOAD_ADD(Bl + w * (BM * NK));
    __syncthreads();
    if (w == 2 || w == 3) ACC_STORE(Al + (w - 2) * (BM * NK));
    __syncthreads();
    if (w < 2)  ACC_LOAD_ADD(Al + w * (BM * NK));
    __syncthreads();
    if (w == 1) ACC_STORE(Bl);
    __syncthreads();
    if (w == 0) {
        ACC_LOAD_ADD(Bl);
#undef ACC_STORE
#undef ACC_LOAD_ADD
        // write partial dots (coalesced) and stats to workspace
        float* dp = ws + WS_DOT + ((size_t)tile * 2 + khalf) * (BM * NK)
                  + (size_t)(rg * 4) * NK + cg * 8;
        #pragma unroll
        for (int r = 0; r < 4; ++r) {
            *(float4*)(dp + r*NK)     = make_float4(acc[r][0],acc[r][1],acc[r][2],acc[r][3]);
            *(float4*)(dp + r*NK + 4) = make_float4(acc[r][4],acc[r][5],acc[r][6],acc[r][7]);
        }
        if (lane < BM) {
            float s = 0.f, q = 0.f;
            #pragma unroll
            for (int w8 = 0; w8 < 8; ++w8) { s += statS[w8][lane]; q += statQ[w8][lane]; }
            ((float2*)(ws + WS_STAT))[((size_t)tile * 2 + khalf) * BM + lane] =
                make_float2(s, q);
        }
    }
}

// ---------------------------------------------------------------------------
// Epilogue: fuse K-halves, distance, min/argmin (packed-key butterfly),
// centroid override (last-write-wins), energy. 128 blocks x 4 waves;
// each wave handles 16 rows; lane = centroid column.
// ---------------------------------------------------------------------------
__global__ __launch_bounds__(256) void epi_kernel(
    const float* __restrict__ ws, const int* __restrict__ cid,
    float* __restrict__ out)
{
    const int lane = threadIdx.x & 63;
    const int wave = threadIdx.x >> 6;
    const int gw   = blockIdx.x * 4 + wave;    // 0..511

    const float cq  = ws[WS_SQC + lane];
    const float cs  = ws[WS_SC + lane];
    const int   myc = cid[lane];

    float esum = 0.f;
    for (int rr = 0; rr < 16; ++rr) {
        const int gi = gw * 16 + rr;
        const int ti = gi >> 5, r = gi & 31;
        const float* dpb = ws + WS_DOT + (size_t)ti * 2 * (BM * NK) + r * NK;
        float dot = dpb[lane] + dpb[BM * NK + lane];
        const float2* st = (const float2*)(ws + WS_STAT);
        float2 s0 = st[(ti * 2 + 0) * BM + r];
        float2 s1 = st[(ti * 2 + 1) * BM + r];
        float qr = s0.y + s1.y, sr = s0.x + s1.x;
        float d2 = qr + cq - 2.f * dot + 2.0e-6f * (sr - cs) + 5.12e-10f;
        float dist = sqrtf(fmaxf(d2, 0.f));
        unsigned long long key =
            (((unsigned long long)__float_as_uint(dist)) << 6) | (unsigned)lane;
        #pragma unroll
        for (int off = 32; off; off >>= 1) {
            unsigned long long o = __shfl_xor(key, off);
            key = (o < key) ? o : key;
        }
        float y = (float)(unsigned)(key & 63ull);
        unsigned long long ball = __ballot(myc == gi);
        if (ball) y = (float)(63 - __clzll(ball));   // last write wins (max k)
        esum += __uint_as_float((unsigned)(key >> 6));
        if (lane == 0) out[1 + gi] = y;
    }
    if (lane == 0) atomicAdd(out, -esum);
}

extern "C" void kernel_launch(void* const* d_in, const int* in_sizes, int n_in,
                              void* d_out, int out_size, void* d_ws, size_t ws_size,
                              hipStream_t stream) {
    const float* f   = (const float*)d_in[0];
    const int*   cid = (const int*)d_in[1];
    float*       out = (float*)d_out;
    float*       ws  = (float*)d_ws;     // ~4.5 MB used

    prep_kernel<<<NK, 64, 0, stream>>>(f, cid, ws, out);
    gemm_kernel<<<2 * NTILE, 512, 0, stream>>>(f, ws);
    epi_kernel<<<NPTS / 64, 256, 0, stream>>>(ws, cid, out);
}

// Round 8
// 37.829 us; speedup vs baseline: 4.4130x; 4.4130x over previous
//
#include <hip/hip_runtime.h>

#define NPTS  8192
#define DIM   512
#define NK    64
#define TM    64            // rows per tile (= lanes)
#define KP    4             // K-split parts
#define KD    (DIM/KP)      // 128 dims per part
#define NT    (NPTS/TM)     // 128 tiles

// workspace layout (float offsets)
#define WS_DOT  0                              // [KP*64][8192] transposed = 2M f
#define WS_STAT (KP * NK * NPTS)               // [KP][8192] float2 = 64K f
#define WS_CTT  (WS_STAT + KP * NPTS * 2)      // [512][64] k-major = 32768 f
#define WS_SQC  (WS_CTT + DIM * NK)            // [64]
#define WS_SC   (WS_SQC + NK)                  // [64]

// ---------------------------------------------------------------------------
// Prep: gather centroid rows into k-major ctT[d][n] (the s_load layout),
// per-centroid stats, zero the energy accumulator.
// ---------------------------------------------------------------------------
__global__ __launch_bounds__(64) void prep_kernel(
    const float* __restrict__ f, const int* __restrict__ cid,
    float* __restrict__ ws, float* __restrict__ out)
{
    const int k = blockIdx.x;      // one wave per centroid
    const int lane = threadIdx.x;
    if (k == 0 && lane == 0) out[0] = 0.f;   // stream order: before epi atomics
    float* ctT = ws + WS_CTT;
    const float* row = f + (size_t)cid[k] * DIM;
    float4 a = *(const float4*)(row + lane * 8);
    float4 b = *(const float4*)(row + lane * 8 + 4);
    const int d = lane * 8;
    ctT[(d+0)*NK + k] = a.x;  ctT[(d+1)*NK + k] = a.y;
    ctT[(d+2)*NK + k] = a.z;  ctT[(d+3)*NK + k] = a.w;
    ctT[(d+4)*NK + k] = b.x;  ctT[(d+5)*NK + k] = b.y;
    ctT[(d+6)*NK + k] = b.z;  ctT[(d+7)*NK + k] = b.w;
    float s = a.x+a.y+a.z+a.w + b.x+b.y+b.z+b.w;
    float q = a.x*a.x+a.y*a.y+a.z*a.z+a.w*a.w
            + b.x*b.x+b.y*b.y+b.z*b.z+b.w*b.w;
    #pragma unroll
    for (int off = 32; off; off >>= 1) {
        s += __shfl_xor(s, off);
        q += __shfl_xor(q, off);
    }
    if (lane == 0) { ws[WS_SQC + k] = q; ws[WS_SC + k] = s; }
}

// ---------------------------------------------------------------------------
// GEMM: 512 blocks (128 tiles x 4 K-parts) x 256 threads. lane <-> row;
// each wave owns 16 centroid COLUMNS -> B addresses are wave-uniform, so B
// streams through s_load into SGPRs (scalar pipe; zero LDS/VMEM-vector cost)
// and v_fma reads the SGPR operand directly. A staged ONCE to LDS (33 KB,
// k4-major, pad 65 -> conflict-free b128 reads), then a BARRIER-FREE main
// loop: per 4-dim group = 1 ds_read_b128 + 16 uniform float4 B loads + 64
// FMAs. acc[16] ~= 40 VGPR, NO min-waves hint (R4/R6 lesson: hints = spill).
// ---------------------------------------------------------------------------
__global__ __launch_bounds__(256) void gemm_kernel(
    const float* __restrict__ f, float* __restrict__ ws)
{
    __shared__ float4 Al4[32 * 65];   // [k4][row] pad 65 -> 33.3 KB

    const int t    = threadIdx.x;
    const int lane = t & 63;
    const int tile  = blockIdx.x >> 2;
    const int kpart = blockIdx.x & 3;
    const int kbase = kpart * KD;
    const int cw = __builtin_amdgcn_readfirstlane((t >> 6) << 4); // col base

    // ---- stage A: 64 rows x 128 dims, k4-major. thread=(row=t>>4, kq=t&15)
    // global: 16 consecutive lanes read 256B of one row (coalesced);
    // LDS write bank = 4*(kq+row)%32 (pad 65) -> mild conflicts, staging only.
    {
        const int srow = t >> 4, skq = t & 15;
        #pragma unroll
        for (int kh = 0; kh < 2; ++kh)
            #pragma unroll
            for (int i = 0; i < 4; ++i) {
                const int row = srow + 16 * i, k4 = skq + 16 * kh;
                Al4[k4 * 65 + row] = *(const float4*)(
                    f + (size_t)(tile * TM + row) * DIM + kbase + k4 * 4);
            }
    }
    __syncthreads();          // the ONLY barrier

    const float* Bg = ws + WS_CTT + (size_t)kbase * NK;  // B[k][64], k local
    float acc[16];
    #pragma unroll
    for (int j = 0; j < 16; ++j) acc[j] = 0.f;
    float sp = 0.f, qp = 0.f;

    #pragma unroll 2
    for (int g = 0; g < 32; ++g) {
        const float4 av = Al4[g * 65 + lane];   // this row, dims 4g..4g+3
        sp += (av.x + av.y) + (av.z + av.w);
        qp = fmaf(av.x, av.x, qp); qp = fmaf(av.y, av.y, qp);
        qp = fmaf(av.z, av.z, qp); qp = fmaf(av.w, av.w, qp);
        #pragma unroll
        for (int kk = 0; kk < 4; ++kk) {
            const float* bp = Bg + (size_t)(g * 4 + kk) * NK + cw; // uniform
            const float4 b0 = *(const float4*)(bp);
            const float4 b1 = *(const float4*)(bp + 4);
            const float4 b2 = *(const float4*)(bp + 8);
            const float4 b3 = *(const float4*)(bp + 12);
            const float a = (kk == 0) ? av.x : (kk == 1) ? av.y
                          : (kk == 2) ? av.z : av.w;
            acc[0]  = fmaf(a, b0.x, acc[0]);  acc[1]  = fmaf(a, b0.y, acc[1]);
            acc[2]  = fmaf(a, b0.z, acc[2]);  acc[3]  = fmaf(a, b0.w, acc[3]);
            acc[4]  = fmaf(a, b1.x, acc[4]);  acc[5]  = fmaf(a, b1.y, acc[5]);
            acc[6]  = fmaf(a, b1.z, acc[6]);  acc[7]  = fmaf(a, b1.w, acc[7]);
            acc[8]  = fmaf(a, b2.x, acc[8]);  acc[9]  = fmaf(a, b2.y, acc[9]);
            acc[10] = fmaf(a, b2.z, acc[10]); acc[11] = fmaf(a, b2.w, acc[11]);
            acc[12] = fmaf(a, b3.x, acc[12]); acc[13] = fmaf(a, b3.y, acc[13]);
            acc[14] = fmaf(a, b3.z, acc[14]); acc[15] = fmaf(a, b3.w, acc[15]);
        }
    }

    // ---- store partial dots TRANSPOSED [kpart*64+col][row]: coalesced b32
    const int gi = tile * TM + lane;
    #pragma unroll
    for (int j = 0; j < 16; ++j)
        ws[WS_DOT + (size_t)((kpart << 6) + cw + j) * NPTS + gi] = acc[j];
    if (t < 64)   // wave 0: per-row stats for this K-part
        ((float2*)(ws + WS_STAT))[(size_t)kpart * NPTS + gi] =
            make_float2(sp, qp);
}

// ---------------------------------------------------------------------------
// Epilogue: 128 blocks x 1 wave; lane <-> point. Sum 4 K-part dots per col
// (coalesced b32 across lanes), distance, sequential strict-< min (= first-
// index argmin), last-write-wins override, energy wave-reduce + atomicAdd.
// ---------------------------------------------------------------------------
__global__ __launch_bounds__(64) void epi_kernel(
    const float* __restrict__ ws, const int* __restrict__ cid,
    float* __restrict__ out)
{
    __shared__ float cqL[NK], csL[NK];
    __shared__ int   cidL[NK];
    const int lane = threadIdx.x;
    const int gi   = blockIdx.x * 64 + lane;

    cqL[lane]  = ws[WS_SQC + lane];
    csL[lane]  = ws[WS_SC + lane];
    cidL[lane] = cid[lane];
    __syncthreads();

    const float2* st = (const float2*)(ws + WS_STAT);
    float s = 0.f, q = 0.f;
    #pragma unroll
    for (int kp = 0; kp < KP; ++kp) {
        float2 v = st[(size_t)kp * NPTS + gi];
        s += v.x; q += v.y;
    }

    float dmin = 3.4e38f;
    int   arg  = 0;
    #pragma unroll 4
    for (int col = 0; col < NK; ++col) {
        const float* dp = ws + WS_DOT + (size_t)col * NPTS + gi;
        float dot = dp[0] + dp[(size_t)64 * NPTS] + dp[(size_t)128 * NPTS]
                  + dp[(size_t)192 * NPTS];
        float d2 = q + cqL[col] - 2.f * dot + 2.0e-6f * (s - csL[col])
                 + 5.12e-10f;
        float dist = sqrtf(fmaxf(d2, 0.f));
        if (dist < dmin) { dmin = dist; arg = col; }   // strict <: first index
    }

    float y = (float)arg;
    for (int k = 0; k < NK; ++k)
        if (cidL[k] == gi) y = (float)k;               // last write wins
    out[1 + gi] = y;

    float e = dmin;
    #pragma unroll
    for (int off = 32; off; off >>= 1) e += __shfl_xor(e, off);
    if (lane == 0) atomicAdd(out, -e);
}

extern "C" void kernel_launch(void* const* d_in, const int* in_sizes, int n_in,
                              void* d_out, int out_size, void* d_ws, size_t ws_size,
                              hipStream_t stream) {
    const float* f   = (const float*)d_in[0];
    const int*   cid = (const int*)d_in[1];
    float*       out = (float*)d_out;
    float*       ws  = (float*)d_ws;     // ~8.8 MB used

    prep_kernel<<<NK, 64, 0, stream>>>(f, cid, ws, out);
    gemm_kernel<<<NT * KP, 256, 0, stream>>>(f, ws);
    epi_kernel<<<NPTS / 64, 64, 0, stream>>>(ws, cid, out);
}

// Round 9
// 34.297 us; speedup vs baseline: 4.8674x; 1.1030x over previous
//
#include <hip/hip_runtime.h>

typedef unsigned long long u64;

#define NPTS 8192
#define DIM  512
#define NK   64
#define TM   64             // rows per tile
#define KP   8              // K-split parts
#define KD   (DIM/KP)       // 64 dims per part
#define NT   (NPTS/TM)      // 128 tiles
#define APAD 68             // A LDS row stride (floats): %4==0 (b128), 2-way banks

// workspace layout (float offsets)
#define WS_DOT  0                         // [KP][NK][NPTS] = 16 MB
#define WS_STAT (KP * NK * NPTS)          // [KP][NPTS] float2
#define WS_CTT  (WS_STAT + KP * NPTS * 2) // [512][64] k-major
#define WS_SQC  (WS_CTT + DIM * NK)       // [64]
#define WS_SC   (WS_SQC + NK)             // [64]

// ---------------------------------------------------------------------------
// Prep: gather centroid rows into k-major ctT[d][n], per-centroid stats,
// zero the energy accumulator (stream-ordered before epi's atomics).
// ---------------------------------------------------------------------------
__global__ __launch_bounds__(64) void prep_kernel(
    const float* __restrict__ f, const int* __restrict__ cid,
    float* __restrict__ ws, float* __restrict__ out)
{
    const int k = blockIdx.x;
    const int lane = threadIdx.x;
    if (k == 0 && lane == 0) out[0] = 0.f;
    float* ctT = ws + WS_CTT;
    const float* row = f + (size_t)cid[k] * DIM;
    float4 a = *(const float4*)(row + lane * 8);
    float4 b = *(const float4*)(row + lane * 8 + 4);
    const int d = lane * 8;
    ctT[(d+0)*NK + k] = a.x;  ctT[(d+1)*NK + k] = a.y;
    ctT[(d+2)*NK + k] = a.z;  ctT[(d+3)*NK + k] = a.w;
    ctT[(d+4)*NK + k] = b.x;  ctT[(d+5)*NK + k] = b.y;
    ctT[(d+6)*NK + k] = b.z;  ctT[(d+7)*NK + k] = b.w;
    float s = a.x+a.y+a.z+a.w + b.x+b.y+b.z+b.w;
    float q = a.x*a.x+a.y*a.y+a.z*a.z+a.w*a.w
            + b.x*b.x+b.y*b.y+b.z*b.z+b.w*b.w;
    #pragma unroll
    for (int off = 32; off; off >>= 1) {
        s += __shfl_xor(s, off);
        q += __shfl_xor(q, off);
    }
    if (lane == 0) { ws[WS_SQC + k] = q; ws[WS_SC + k] = s; }
}

// ---------------------------------------------------------------------------
// GEMM: 1024 blocks (128 tiles x 8 K-parts) x 256 threads = 4096 waves =
// 4 waves/SIMD (every prior round ran <=2 and was latency-bound). Per block:
// 64x64 tile over 64 dims; A(17.4KB,k-major) + B(16KB) staged once, ONE
// barrier, then 64 k-steps of 2x ds_read_b128 + 16 FMA (acc[4][4], ~50 VGPR,
// no min-waves hint). LDS 33.4KB -> 4 blocks/CU = 16 waves/CU.
// Partial dots stored [kp][col][point] (coalesced float4); per-kpart row
// stats ride on the A staging loads.
// ---------------------------------------------------------------------------
__global__ __launch_bounds__(256) void gemm_kernel(
    const float* __restrict__ f, float* __restrict__ ws)
{
    __shared__ float Al[KD * APAD];     // [k][row], pad 68
    __shared__ float Bl[KD * NK];       // [k][col]

    const int t     = threadIdx.x;
    const int tile  = blockIdx.x >> 3;
    const int kp    = blockIdx.x & 7;
    const int kbase = kp * KD;

    // ---- stage A: thread (srow=t>>2, sq=t&3) reads 64B contiguous ----
    const int srow = t >> 2, sq = t & 3;
    const float* fr = f + (size_t)(tile * TM + srow) * DIM + kbase + sq * 16;
    float4 a0 = *(const float4*)(fr);
    float4 a1 = *(const float4*)(fr + 4);
    float4 a2 = *(const float4*)(fr + 8);
    float4 a3 = *(const float4*)(fr + 12);

    float sp = 0.f, qp = 0.f;
#define STAT4(v) do { sp += (v.x+v.y)+(v.z+v.w); \
        qp = fmaf(v.x,v.x,qp); qp = fmaf(v.y,v.y,qp); \
        qp = fmaf(v.z,v.z,qp); qp = fmaf(v.w,v.w,qp); } while (0)
    STAT4(a0); STAT4(a1); STAT4(a2); STAT4(a3);
#undef STAT4
    sp += __shfl_xor(sp, 1); sp += __shfl_xor(sp, 2);
    qp += __shfl_xor(qp, 1); qp += __shfl_xor(qp, 2);

#define AW(j, v) do { const int d_ = sq * 16 + (j) * 4; \
        Al[(d_+0)*APAD + srow] = v.x; Al[(d_+1)*APAD + srow] = v.y; \
        Al[(d_+2)*APAD + srow] = v.z; Al[(d_+3)*APAD + srow] = v.w; } while (0)
    AW(0, a0); AW(1, a1); AW(2, a2); AW(3, a3);
#undef AW

    // ---- stage B: linear 16KB copy of ctT rows kbase..kbase+63 ----
    {
        const float* Bg = ws + WS_CTT + (size_t)kbase * NK;
        #pragma unroll
        for (int j = 0; j < 4; ++j)
            *(float4*)&Bl[(t + 256 * j) * 4] =
                *(const float4*)(Bg + (size_t)(t + 256 * j) * 4);
    }
    __syncthreads();          // the only barrier

    // ---- compute: lane -> (tr=lane&15 -> rows 4tr.., tc: cols 4(tc+4w)..)
    const int lane = t & 63;
    const int w    = t >> 6;
    const int tr   = lane & 15;
    const int cb   = 4 * ((lane >> 4) + 4 * w);   // col base
    float acc[4][4];
    #pragma unroll
    for (int r = 0; r < 4; ++r)
        #pragma unroll
        for (int c = 0; c < 4; ++c) acc[r][c] = 0.f;

    #pragma unroll 16
    for (int k = 0; k < KD; ++k) {
        const float4 a4 = *(const float4*)&Al[k * APAD + 4 * tr];
        const float4 b4 = *(const float4*)&Bl[k * NK + cb];
        const float av[4] = {a4.x, a4.y, a4.z, a4.w};
        #pragma unroll
        for (int r = 0; r < 4; ++r) {
            acc[r][0] = fmaf(av[r], b4.x, acc[r][0]);
            acc[r][1] = fmaf(av[r], b4.y, acc[r][1]);
            acc[r][2] = fmaf(av[r], b4.z, acc[r][2]);
            acc[r][3] = fmaf(av[r], b4.w, acc[r][3]);
        }
    }

    // ---- store partials [kp][col][point]: float4 over 4 rows, coalesced ----
    const int pbase = tile * TM + 4 * tr;
    #pragma unroll
    for (int c = 0; c < 4; ++c) {
        *(float4*)(ws + WS_DOT + ((size_t)(kp * NK + cb + c)) * NPTS + pbase) =
            make_float4(acc[0][c], acc[1][c], acc[2][c], acc[3][c]);
    }
    if (sq == 0)
        ((float2*)(ws + WS_STAT))[(size_t)kp * NPTS + tile * TM + srow] =
            make_float2(sp, qp);
}

// ---------------------------------------------------------------------------
// Epilogue: 128 blocks x 256 threads (512 waves). lane <-> point; wave w owns
// cols 16w..16w+15. Coalesced b32 partial-dot sums, packed-key min (first-
// index tie-break), cross-wave combine via LDS, last-write-wins override,
// energy wave-reduce + one atomicAdd per block.
// ---------------------------------------------------------------------------
__global__ __launch_bounds__(256) void epi_kernel(
    const float* __restrict__ ws, const int* __restrict__ cid,
    float* __restrict__ out)
{
    __shared__ u64   keys[4][TM];
    __shared__ float cqL[NK], csL[NK];
    __shared__ int   cidL[NK];

    const int t    = threadIdx.x;
    const int lane = t & 63;
    const int w    = t >> 6;
    const int gi   = blockIdx.x * TM + lane;

    if (t < NK) { cqL[t] = ws[WS_SQC + t]; csL[t] = ws[WS_SC + t];
                  cidL[t] = cid[t]; }

    // point stats: sum the 8 K-part partials (coalesced float2)
    float s = 0.f, q = 0.f;
    #pragma unroll
    for (int kp = 0; kp < KP; ++kp) {
        float2 v = ((const float2*)(ws + WS_STAT))[(size_t)kp * NPTS + gi];
        s += v.x; q += v.y;
    }
    __syncthreads();

    u64 key = ~0ull;
    #pragma unroll 4
    for (int c = 0; c < 16; ++c) {
        const int col = w * 16 + c;
        float dot = 0.f;
        #pragma unroll
        for (int kp = 0; kp < KP; ++kp)
            dot += ws[WS_DOT + ((size_t)(kp * NK + col)) * NPTS + gi];
        float d2 = q + cqL[col] - 2.f * dot + 2.0e-6f * (s - csL[col])
                 + 5.12e-10f;
        float dist = sqrtf(fmaxf(d2, 0.f));
        u64 kk = (((u64)__float_as_uint(dist)) << 6) | (unsigned)col;
        key = (kk < key) ? kk : key;
    }
    keys[w][lane] = key;
    __syncthreads();

    if (w == 0) {
        #pragma unroll
        for (int j = 1; j < 4; ++j) {
            u64 o = keys[j][lane];
            key = (o < key) ? o : key;
        }
        float y = (float)(unsigned)(key & 63ull);
        for (int k = 0; k < NK; ++k)
            if (cidL[k] == gi) y = (float)k;           // last write wins
        out[1 + gi] = y;
        float e = __uint_as_float((unsigned)(key >> 6));
        #pragma unroll
        for (int off = 32; off; off >>= 1) e += __shfl_xor(e, off);
        if (lane == 0) atomicAdd(out, -e);
    }
}

extern "C" void kernel_launch(void* const* d_in, const int* in_sizes, int n_in,
                              void* d_out, int out_size, void* d_ws, size_t ws_size,
                              hipStream_t stream) {
    const float* f   = (const float*)d_in[0];
    const int*   cid = (const int*)d_in[1];
    float*       out = (float*)d_out;
    float*       ws  = (float*)d_ws;     // ~17.4 MB used

    prep_kernel<<<NK, 64, 0, stream>>>(f, cid, ws, out);
    gemm_kernel<<<NT * KP, 256, 0, stream>>>(f, ws);
    epi_kernel<<<NT, 256, 0, stream>>>(ws, cid, out);
}